// Round 3
// baseline (353.376 us; speedup 1.0000x reference)
//
#include <hip/hip_runtime.h>
#include <hip/hip_bf16.h>

constexpr int NZ   = 300, NX = 500, NPAD = 40;
constexpr int NZP  = NZ + NPAD;          // 340
constexpr int NXP  = NX + 2 * NPAD;      // 580
constexpr int Bdim = 2, Cdim = 8;
constexpr int HW   = NZP * NXP;          // 197200
constexpr int S    = Bdim * Cdim * HW;   // 3155200 (divisible by 256: 12325 blocks)
constexpr float DT = 1e-3f;
constexpr float A2 = (float)((1.0 / 24.0) / 10.0);   // a/DX
constexpr float B2 = (float)((9.0 / 8.0) / 10.0);    // b/DX
constexpr float COEF = 0.43173470493638357f;         // -ln(1e-5)*3*4000/(2*(DX*NPAD)^2)

__device__ __forceinline__ float dax_of(int j) {
    float ax = 1.0f;
    if (j < NPAD)                { int r = NPAD - 1 - j;      ax = COEF * (float)(r * r); }
    else if (j >= NX + NPAD)     { int r = j - (NX + NPAD);   ax = COEF * (float)(r * r); }
    return 1.0f - DT * ax;
}
__device__ __forceinline__ float daz_of(int i) {
    float az = 1.0f;
    if (i >= NZ)                 { int r = i - NZ;            az = COEF * (float)(r * r); }
    return 1.0f - DT * az;
}

// ---------------- Kernel 1: velocity update (PML split) ----------------
__global__ __launch_bounds__(256) void k_vel(
    const float* __restrict__ txx, const float* __restrict__ tzz, const float* __restrict__ txz,
    const float* __restrict__ vx_x, const float* __restrict__ vx_z,
    const float* __restrict__ vz_x, const float* __restrict__ vz_z,
    const float* __restrict__ rho,
    const float* __restrict__ fs, const int* __restrict__ zs, const int* __restrict__ xs,
    float* __restrict__ out)
{
    int idx = blockIdx.x * 256 + threadIdx.x;
    if (idx >= S) return;
    int j  = idx % NXP;
    int t  = idx / NXP;
    int i  = t % NZP;
    int bc = t / NZP;
    int c  = bc % Cdim;
    int b  = bc / Cdim;
    const float* TXX = txx + bc * HW;
    const float* TZZ = tzz + bc * HW;
    const float* TXZ = txz + bc * HW;
    int p = i * NXP + j;

    // txx: x-window j-1..j+2 (KX)
    float txx_jm1 = (j >= 1)      ? TXX[p - 1] : 0.0f;
    float txx_0   =                 TXX[p];
    float txx_jp1 = (j + 1 < NXP) ? TXX[p + 1] : 0.0f;
    float txx_jp2 = (j + 2 < NXP) ? TXX[p + 2] : 0.0f;

    // txz: x-window j-2..j+1 (KXU), z-window i-2..i+1 (KZU)
    float txz_jm2 = (j >= 2)      ? TXZ[p - 2] : 0.0f;
    float txz_jm1 = (j >= 1)      ? TXZ[p - 1] : 0.0f;
    float txz_0   =                 TXZ[p];
    float txz_jp1 = (j + 1 < NXP) ? TXZ[p + 1] : 0.0f;
    float txz_im2 = (i >= 2)      ? TXZ[p - 2 * NXP] : 0.0f;
    float txz_im1 = (i >= 1)      ? TXZ[p - NXP]     : 0.0f;
    float txz_ip1 = (i + 1 < NZP) ? TXZ[p + NXP]     : 0.0f;

    // tzz: z-window i-1..i+2 (KZ), with point-source injection
    float tzz_im1 = (i >= 1)      ? TZZ[p - NXP]     : 0.0f;
    float tzz_0   =                 TZZ[p];
    float tzz_ip1 = (i + 1 < NZP) ? TZZ[p + NXP]     : 0.0f;
    float tzz_ip2 = (i + 2 < NZP) ? TZZ[p + 2 * NXP] : 0.0f;
    {
        int sz = zs[c];
        int sx = xs[c] + NPAD;
        if (j == sx) {
            float fsb = fs[b];
            if (i - 1 == sz) tzz_im1 += fsb;
            if (i     == sz) tzz_0   += fsb;
            if (i + 1 == sz) tzz_ip1 += fsb;
            if (i + 2 == sz) tzz_ip2 += fsb;
        }
    }

    float rinv = 1.0f / rho[b * HW + p];

    float var_txx_x = (A2 * (txx_jm1 - txx_jp2) + B2 * (txx_jp1 - txx_0  )) * rinv; // KX
    float var_txz_z = (A2 * (txz_im2 - txz_ip1) + B2 * (txz_0   - txz_im1)) * rinv; // KZU
    float var_txz_x = (A2 * (txz_jm2 - txz_jp1) + B2 * (txz_0   - txz_jm1)) * rinv; // KXU
    float var_tzz_z = (A2 * (tzz_im1 - tzz_ip2) + B2 * (tzz_ip1 - tzz_0  )) * rinv; // KZ

    float dax = dax_of(j), daz = daz_of(i);
    float nvx_x = dax * vx_x[idx] + DT * var_txx_x;
    float nvx_z = daz * vx_z[idx] + DT * var_txz_z;
    float nvz_x = dax * vz_x[idx] + DT * var_txz_x;
    float nvz_z = daz * vz_z[idx] + DT * var_tzz_z;

    out[0 * (long)S + idx] = nvx_x + nvx_z;  // vx
    out[1 * (long)S + idx] = nvz_x + nvz_z;  // vz
    out[5 * (long)S + idx] = nvx_x;
    out[6 * (long)S + idx] = nvx_z;
    out[7 * (long)S + idx] = nvz_x;
    out[8 * (long)S + idx] = nvz_z;
}

// ---------------- Kernel 2: stress update (PML split) ----------------
__global__ __launch_bounds__(256) void k_stress(
    const float* __restrict__ txx_x, const float* __restrict__ txx_z,
    const float* __restrict__ tzz_x, const float* __restrict__ tzz_z,
    const float* __restrict__ txz_x, const float* __restrict__ txz_z,
    const float* __restrict__ vp, const float* __restrict__ vs, const float* __restrict__ rho,
    float* __restrict__ out)
{
    int idx = blockIdx.x * 256 + threadIdx.x;
    if (idx >= S) return;
    int j  = idx % NXP;
    int t  = idx / NXP;
    int i  = t % NZP;
    int bc = t / NZP;
    int b  = bc / Cdim;
    const float* VX = out + 0 * (long)S + bc * HW;
    const float* VZ = out + 1 * (long)S + bc * HW;
    int p = i * NXP + j;

    // vx: x-window j-2..j+1 (KXU), z-window i-1..i+2 (KZ)
    float vx_jm2 = (j >= 2)      ? VX[p - 2] : 0.0f;
    float vx_jm1 = (j >= 1)      ? VX[p - 1] : 0.0f;
    float vx_0   =                 VX[p];
    float vx_jp1 = (j + 1 < NXP) ? VX[p + 1] : 0.0f;
    float vx_im1 = (i >= 1)      ? VX[p - NXP]     : 0.0f;
    float vx_ip1 = (i + 1 < NZP) ? VX[p + NXP]     : 0.0f;
    float vx_ip2 = (i + 2 < NZP) ? VX[p + 2 * NXP] : 0.0f;

    // vz: x-window j-1..j+2 (KX), z-window i-2..i+1 (KZU)
    float vz_jm1 = (j >= 1)      ? VZ[p - 1] : 0.0f;
    float vz_0   =                 VZ[p];
    float vz_jp1 = (j + 1 < NXP) ? VZ[p + 1] : 0.0f;
    float vz_jp2 = (j + 2 < NXP) ? VZ[p + 2] : 0.0f;
    float vz_im2 = (i >= 2)      ? VZ[p - 2 * NXP] : 0.0f;
    float vz_im1 = (i >= 1)      ? VZ[p - NXP]     : 0.0f;
    float vz_ip1 = (i + 1 < NZP) ? VZ[p + NXP]     : 0.0f;

    float var_vx_x = A2 * (vx_jm2 - vx_jp1) + B2 * (vx_0   - vx_jm1); // KXU
    float var_vx_z = A2 * (vx_im1 - vx_ip2) + B2 * (vx_ip1 - vx_0  ); // KZ
    float var_vz_x = A2 * (vz_jm1 - vz_jp2) + B2 * (vz_jp1 - vz_0  ); // KX
    float var_vz_z = A2 * (vz_im2 - vz_ip1) + B2 * (vz_0   - vz_im1); // KZU

    int mp = b * HW + p;
    float vpv = vp[mp], vsv = vs[mp], rh = rho[mp];
    float lam2mu = vpv * vpv * rh;
    float mu     = vsv * vsv * rh;
    float lam    = lam2mu - 2.0f * mu;

    float dax = dax_of(j), daz = daz_of(i);

    float ntxx_x = dax * txx_x[idx] + DT * lam2mu * var_vx_x;
    float ntxx_z = daz * txx_z[idx] + DT * lam    * var_vz_z;
    float ntzz_x = dax * tzz_x[idx] + DT * lam    * var_vx_x;
    float ntzz_z = daz * tzz_z[idx] + DT * lam2mu * var_vz_z;
    float ntxz_x = dax * txz_x[idx] + DT * mu     * var_vz_x;
    float ntxz_z = daz * txz_z[idx] + DT * mu     * var_vx_z;

    out[ 2 * (long)S + idx] = ntxx_x + ntxx_z;  // txx
    out[ 3 * (long)S + idx] = ntzz_x + ntzz_z;  // tzz
    out[ 4 * (long)S + idx] = ntxz_x + ntxz_z;  // txz
    out[ 9 * (long)S + idx] = ntxx_x;
    out[10 * (long)S + idx] = ntxx_z;
    out[11 * (long)S + idx] = ntzz_x;
    out[12 * (long)S + idx] = ntzz_z;
    out[13 * (long)S + idx] = ntxz_x;
    out[14 * (long)S + idx] = ntxz_z;
}

extern "C" void kernel_launch(void* const* d_in, const int* in_sizes, int n_in,
                              void* d_out, int out_size, void* d_ws, size_t ws_size,
                              hipStream_t stream) {
    // setup_inputs() dict order; all float tensors are float32 buffers, indices int32.
    const float* txx   = (const float*)d_in[0];
    const float* tzz   = (const float*)d_in[1];
    const float* txz   = (const float*)d_in[2];
    const float* vx_x  = (const float*)d_in[3];
    const float* vx_z  = (const float*)d_in[4];
    const float* vz_x  = (const float*)d_in[5];
    const float* vz_z  = (const float*)d_in[6];
    const float* txx_x = (const float*)d_in[7];
    const float* txx_z = (const float*)d_in[8];
    const float* tzz_x = (const float*)d_in[9];
    const float* tzz_z = (const float*)d_in[10];
    const float* txz_x = (const float*)d_in[11];
    const float* txz_z = (const float*)d_in[12];
    const float* vp    = (const float*)d_in[13];
    const float* vs    = (const float*)d_in[14];
    const float* rho   = (const float*)d_in[15];
    const float* fs    = (const float*)d_in[16];
    const int*   zs    = (const int*)d_in[17];
    const int*   xs    = (const int*)d_in[18];
    float* out = (float*)d_out;   // reference output dtype is float32

    dim3 grid(S / 256), block(256);
    k_vel<<<grid, block, 0, stream>>>(txx, tzz, txz, vx_x, vx_z, vz_x, vz_z,
                                      rho, fs, zs, xs, out);
    k_stress<<<grid, block, 0, stream>>>(txx_x, txx_z, tzz_x, tzz_z, txz_x, txz_z,
                                         vp, vs, rho, out);
}